// Round 7
// baseline (238.268 us; speedup 1.0000x reference)
//
#include <hip/hip_runtime.h>

// Fused SSIM, B=64, C=1, 512x512 fp32, 11x11 separable Gaussian.
// R15 = R8 geometry (the measured-best base, 64.4us) + every verified fix
// from R11-R14, none of which had been applied to this geometry:
//  - BH=64, CHUNK=8, grid 8x64=512 blocks -> ALL resident (2/CU), 1
//    generation, no tail; per-chunk overheads amortized over 8 rows.
//  - Zero-conflict b64 h-conv reads (R13-verified fix, counter 3.67M->10k):
//    SROW=537 -> row stride 1074 words = 18 (mod 32); rr=tid&7, c0=(tid>>3)*8;
//    base banks 18rr mod 16 all-distinct, +16g covers all even bases; each
//    b64 instr = 4 words/bank = provable minimum. SROW odd forces b64
//    (odd-rr rows are 8 mod 16 bytes) so the analyzed class is what's emitted.
//    Also deletes the float4->f32x2 unpack (~72 movs/chunk).
//  - 1-chunk-ahead register prefetch + non-draining lgkm-only barriers:
//    loads issued at top of chunk k, consumed top of k+1 (~full-chunk
//    distance), never drained by a barrier.
// Single-buffered LDS (dbuf proved neutral in R11): v(k) -> barA -> h(k) ->
// barB; barA = own-writes visible (lgkmcnt0+barrier), barB = own-reads done
// (lgkmcnt0+barrier) before next chunk's overwrite. vmcnt crosses both.

#define IMG 512
#define BH 64            // band height (output rows per block)
#define CHUNK 8
#define NCHUNK (BH / CHUNK)     // 8
#define SROW 537         // f32x2 per row: 5 pad + 512 + 5 pad + 15 bank-pad
                         // stride = 1074 words; 1074 % 32 = 18 -> all-bank class
#define NTHREADS 512
#define GRIDX (IMG / BH)        // 8

typedef __attribute__((ext_vector_type(2))) float f32x2;

static __device__ __forceinline__ f32x2 pk_fma(f32x2 a, f32x2 b, f32x2 c) {
    f32x2 d;
    asm("v_pk_fma_f32 %0, %1, %2, %3" : "=v"(d) : "v"(a), "v"(b), "v"(c));
    return d;
}
static __device__ __forceinline__ f32x2 pk_mul(f32x2 a, f32x2 b) {
    f32x2 d;
    asm("v_pk_mul_f32 %0, %1, %2" : "=v"(d) : "v"(a), "v"(b));
    return d;
}

// Barrier that does NOT drain vmcnt: LDS ops ordered (lgkmcnt(0) + memory
// fences), global register-loads stay in flight across it.
static __device__ __forceinline__ void block_sync_lgkm() {
    asm volatile("s_waitcnt lgkmcnt(0)" ::: "memory");
    __builtin_amdgcn_s_barrier();
    asm volatile("" ::: "memory");
}

__global__ __launch_bounds__(NTHREADS, 4) void ssim_band(
    const float* __restrict__ x, const float* __restrict__ y,
    const float* __restrict__ win, float* __restrict__ partial)
{
    __shared__ __align__(16) f32x2 vab[CHUNK][SROW];   // v-conv of (s, d)
    __shared__ __align__(16) f32x2 vqq[CHUNK][SROW];   // v-conv of (s^2, d^2)
    __shared__ float sg[11];
    __shared__ float redbuf[NTHREADS / 64];

    const int tid = threadIdx.x;

    // 1D kernel g[i] = row sums of the 2D window (exact since sum(g)==1).
    if (tid < 11) {
        float s = 0.f;
        #pragma unroll
        for (int j = 0; j < 11; ++j) s += win[tid * 11 + j];
        sg[tid] = s;
    }
    // Zero the pad columns once (LDS is re-poisoned every launch).
    // 2 planes * 8 rows * 10 pad cols = 160 entries.
    // (Stored cols 522..536 are bank padding, never read -> no init needed.)
    if (tid < 160) {
        int plane = tid / 80, rem = tid % 80, row = rem / 10, pc = rem % 10;
        int cc = (pc < 5) ? pc : (512 + pc);   // stored cols 0..4, 517..521
        f32x2 z = (f32x2)(0.f);
        if (plane == 0) vab[row][cc] = z; else vqq[row][cc] = z;
    }

    const int y0 = blockIdx.x * BH;
    const size_t img_off = (size_t)blockIdx.y * (IMG * IMG);
    const float* __restrict__ xb = x + img_off + tid;   // lane-column base
    const float* __restrict__ yb = y + img_off + tid;

    // Prologue: input rows y0-5 .. y0+12 -> pab[0..17] (chunk 0 window).
    // gy block-uniform -> scalar branch; upper bound never hit in prologue
    // (y0+12 <= 460).
    f32x2 pab[18];
    #pragma unroll
    for (int j = 0; j < 18; ++j) {
        int gy = y0 - 5 + j;
        float a = 0.f, b = 0.f;
        if (gy >= 0) { a = xb[gy * IMG]; b = yb[gy * IMG]; }
        pab[j][0] = a + b;
        pab[j][1] = a - b;
    }

    // Prefetch chunk 1's new rows (y0+13 .. y0+20) into registers.
    float pfa[8], pfb[8];
    #pragma unroll
    for (int j = 0; j < 8; ++j) {
        int gy = y0 + 13 + j;      // block-uniform; <= 468 here, guard anyway
        pfa[j] = 0.f; pfb[j] = 0.f;
        if (gy < IMG) { pfa[j] = xb[gy * IMG]; pfb[j] = yb[gy * IMG]; }
    }

    block_sync_lgkm();   // sg + pad zeros visible; prefetch stays in flight
    f32x2 g2[11];
    #pragma unroll
    for (int k = 0; k < 11; ++k) { float gv = sg[k]; g2[k][0] = gv; g2[k][1] = gv; }

    const float C1 = 1.0e-4f;
    const float C2 = 9.0e-4f;
    float acc = 0.f;

    const int rr = tid & 7;            // h-conv row: varies within the wave
    const int c0 = (tid >> 3) * 8;     // h-conv output col base

    #pragma unroll 1
    for (int k = 0; k < NCHUNK; ++k) {
        if (k) {
            // Slide window down 8 rows; consume prefetched rows.
            #pragma unroll
            for (int j = 0; j < 10; ++j) pab[j] = pab[j + 8];
            #pragma unroll
            for (int j = 0; j < 8; ++j) {
                pab[10 + j][0] = pfa[j] + pfb[j];
                pab[10 + j][1] = pfa[j] - pfb[j];
            }
        }
        // Issue prefetch for chunk k+1's new rows; consumed next chunk, in
        // flight across both (non-draining) barriers.
        if (k < NCHUNK - 1) {
            int rbase = y0 + 8 * k + 13;
            #pragma unroll
            for (int j = 0; j < 8; ++j) {
                int gy = rbase + j;    // block-uniform
                pfa[j] = 0.f; pfb[j] = 0.f;
                if (gy < IMG) { pfa[j] = xb[gy * IMG]; pfb[j] = yb[gy * IMG]; }
            }
        }

        // Squares of the 18-row window.
        f32x2 sq[18];
        #pragma unroll
        for (int j = 0; j < 18; ++j) sq[j] = pk_mul(pab[j], pab[j]);

        // Vertical conv: 8 output rows -> LDS (stored col = image col + 5).
        #pragma unroll
        for (int i = 0; i < CHUNK; ++i) {
            f32x2 a = (f32x2)(0.f), q = (f32x2)(0.f);
            #pragma unroll
            for (int t = 0; t < 11; ++t) {
                a = pk_fma(g2[t], pab[i + t], a);
                q = pk_fma(g2[t], sq[i + t], q);
            }
            vab[i][tid + 5] = a;
            vqq[i][tid + 5] = q;
        }

        block_sync_lgkm();   // writes visible; vmcnt untouched

        // Horizontal conv + SSIM: 8 outputs per lane (row rr, cols c0..c0+7).
        // Out col c taps stored cols c..c+10; lane reads stored c0..c0+17
        // as 18 ds_read_b64 straight into pk_fma operands.
        {
            f32x2 mu[8], qq8[8];
            {
                const f32x2* p = &vab[rr][c0];
                f32x2 t[18];
                #pragma unroll
                for (int i = 0; i < 18; ++i) t[i] = p[i];
                #pragma unroll
                for (int i = 0; i < 8; ++i) {
                    f32x2 a = (f32x2)(0.f);
                    #pragma unroll
                    for (int t1 = 0; t1 < 11; ++t1) a = pk_fma(g2[t1], t[i + t1], a);
                    mu[i] = a;
                }
            }
            {
                const f32x2* p = &vqq[rr][c0];
                f32x2 t[18];
                #pragma unroll
                for (int i = 0; i < 18; ++i) t[i] = p[i];
                #pragma unroll
                for (int i = 0; i < 8; ++i) {
                    f32x2 a = (f32x2)(0.f);
                    #pragma unroll
                    for (int t1 = 0; t1 < 11; ++t1) a = pk_fma(g2[t1], t[i + t1], a);
                    qq8[i] = a;
                }
            }

            #pragma unroll
            for (int i = 0; i < 8; ++i) {
                // mu[i] = (ms, md); qq8[i] = (Ess, Edd)
                f32x2 m2 = pk_mul(mu[i], mu[i]);      // (ms^2, md^2)
                float P = m2[0] + m2[1];              // 2(mxx+myy)
                float Q = m2[0] - m2[1];              // 4 mxy
                float R = qq8[i][0] + qq8[i][1];      // 2(exx+eyy)
                float S = qq8[i][0] - qq8[i][1];      // 4 exy
                float num1 = fmaf(0.5f, Q, C1);
                float num2 = fmaf(0.5f, S - Q, C2);
                float den1 = fmaf(0.5f, P, C1);
                float den2 = fmaf(0.5f, R - P, C2);
                acc += (num1 * num2) * __builtin_amdgcn_rcpf(den1 * den2);
            }
        }

        // Reads done before next chunk's v-conv overwrites; vmcnt untouched.
        if (k < NCHUNK - 1) block_sync_lgkm();
    }

    // Block reduction (cold path: standard barrier fine).
    #pragma unroll
    for (int off = 32; off > 0; off >>= 1) acc += __shfl_down(acc, off, 64);
    int wid = tid >> 6, lane = tid & 63;
    if (lane == 0) redbuf[wid] = acc;
    __syncthreads();
    if (tid == 0) {
        float ssum = 0.f;
        #pragma unroll
        for (int w = 0; w < NTHREADS / 64; ++w) ssum += redbuf[w];
        partial[blockIdx.y * gridDim.x + blockIdx.x] = ssum;
    }
}

__global__ __launch_bounds__(512) void ssim_finalize(
    const float* __restrict__ partial, float* __restrict__ out)
{
    __shared__ double red[8];
    double acc = (double)partial[threadIdx.x];   // 512 partials (8 x 64 grid)
    #pragma unroll
    for (int off = 32; off > 0; off >>= 1) acc += __shfl_down(acc, off, 64);
    int wid = threadIdx.x >> 6, lane = threadIdx.x & 63;
    if (lane == 0) red[wid] = acc;
    __syncthreads();
    if (threadIdx.x == 0) {
        double ssum = 0.0;
        #pragma unroll
        for (int w = 0; w < 8; ++w) ssum += red[w];
        out[0] = (float)(ssum / (64.0 * 512.0 * 512.0));
    }
}

extern "C" void kernel_launch(void* const* d_in, const int* in_sizes, int n_in,
                              void* d_out, int out_size, void* d_ws, size_t ws_size,
                              hipStream_t stream) {
    (void)in_sizes; (void)n_in; (void)out_size; (void)ws_size;
    const float* x   = (const float*)d_in[0];
    const float* y   = (const float*)d_in[1];
    const float* win = (const float*)d_in[2];
    float* out = (float*)d_out;
    float* partial = (float*)d_ws;     // 512 floats

    dim3 grid(GRIDX, 64);              // 8 x 64 = 512 blocks, 2/CU, all resident
    ssim_band<<<grid, NTHREADS, 0, stream>>>(x, y, win, partial);
    ssim_finalize<<<1, 512, 0, stream>>>(partial, out);
}

// Round 8
// 198.200 us; speedup vs baseline: 1.2022x; 1.2022x over previous
//
#include <hip/hip_runtime.h>

// Fused SSIM, B=64, C=1, 512x512 fp32, 11x11 separable Gaussian.
// R16 = R15 with the REAL register cap fixed.
// Decisive evidence on __launch_bounds__ semantics (HIP = CUDA-style,
// 2nd arg = min BLOCKS per CU, not waves/EU):
//   (512,8) -> VGPR capped 32 (R9, spilled);  (512,4) -> capped 64
//   (R8..R15: 44..64, never more; R15's CHUNK=8 live set spilled AT 64).
// => every prior round ran under a 64-VGPR ceiling while LDS held occupancy
// to 2 blocks/CU anyway (128 VGPR free). (512,2) -> cap 128: same occupancy,
// real scheduling headroom. Only change vs R15.
// Carried: BH=64/CHUNK=8 grid 8x64 (best base, all-resident), SROW=537
// zero-conflict b64 class (verified: conflicts 3.67M->5k), 1-chunk-ahead
// register prefetch, non-draining lgkm-only barriers.

#define IMG 512
#define BH 64            // band height (output rows per block)
#define CHUNK 8
#define NCHUNK (BH / CHUNK)     // 8
#define SROW 537         // f32x2 per row: 5 pad + 512 + 5 pad + 15 bank-pad
                         // stride = 1074 words; 1074 % 32 = 18 -> all-bank class
#define NTHREADS 512
#define GRIDX (IMG / BH)        // 8

typedef __attribute__((ext_vector_type(2))) float f32x2;

static __device__ __forceinline__ f32x2 pk_fma(f32x2 a, f32x2 b, f32x2 c) {
    f32x2 d;
    asm("v_pk_fma_f32 %0, %1, %2, %3" : "=v"(d) : "v"(a), "v"(b), "v"(c));
    return d;
}
static __device__ __forceinline__ f32x2 pk_mul(f32x2 a, f32x2 b) {
    f32x2 d;
    asm("v_pk_mul_f32 %0, %1, %2" : "=v"(d) : "v"(a), "v"(b));
    return d;
}

// Barrier that does NOT drain vmcnt: LDS ops ordered (lgkmcnt(0) + memory
// fences), global register-loads stay in flight across it.
static __device__ __forceinline__ void block_sync_lgkm() {
    asm volatile("s_waitcnt lgkmcnt(0)" ::: "memory");
    __builtin_amdgcn_s_barrier();
    asm volatile("" ::: "memory");
}

__global__ __launch_bounds__(NTHREADS, 2) void ssim_band(
    const float* __restrict__ x, const float* __restrict__ y,
    const float* __restrict__ win, float* __restrict__ partial)
{
    __shared__ __align__(16) f32x2 vab[CHUNK][SROW];   // v-conv of (s, d)
    __shared__ __align__(16) f32x2 vqq[CHUNK][SROW];   // v-conv of (s^2, d^2)
    __shared__ float sg[11];
    __shared__ float redbuf[NTHREADS / 64];

    const int tid = threadIdx.x;

    // 1D kernel g[i] = row sums of the 2D window (exact since sum(g)==1).
    if (tid < 11) {
        float s = 0.f;
        #pragma unroll
        for (int j = 0; j < 11; ++j) s += win[tid * 11 + j];
        sg[tid] = s;
    }
    // Zero the pad columns once (LDS is re-poisoned every launch).
    // 2 planes * 8 rows * 10 pad cols = 160 entries.
    // (Stored cols 522..536 are bank padding, never read -> no init needed.)
    if (tid < 160) {
        int plane = tid / 80, rem = tid % 80, row = rem / 10, pc = rem % 10;
        int cc = (pc < 5) ? pc : (512 + pc);   // stored cols 0..4, 517..521
        f32x2 z = (f32x2)(0.f);
        if (plane == 0) vab[row][cc] = z; else vqq[row][cc] = z;
    }

    const int y0 = blockIdx.x * BH;
    const size_t img_off = (size_t)blockIdx.y * (IMG * IMG);
    const float* __restrict__ xb = x + img_off + tid;   // lane-column base
    const float* __restrict__ yb = y + img_off + tid;

    // Prologue: input rows y0-5 .. y0+12 -> pab[0..17] (chunk 0 window).
    // gy block-uniform -> scalar branch; upper bound never hit in prologue.
    f32x2 pab[18];
    #pragma unroll
    for (int j = 0; j < 18; ++j) {
        int gy = y0 - 5 + j;
        float a = 0.f, b = 0.f;
        if (gy >= 0) { a = xb[gy * IMG]; b = yb[gy * IMG]; }
        pab[j][0] = a + b;
        pab[j][1] = a - b;
    }

    // Prefetch chunk 1's new rows (y0+13 .. y0+20) into registers.
    float pfa[8], pfb[8];
    #pragma unroll
    for (int j = 0; j < 8; ++j) {
        int gy = y0 + 13 + j;      // block-uniform
        pfa[j] = 0.f; pfb[j] = 0.f;
        if (gy < IMG) { pfa[j] = xb[gy * IMG]; pfb[j] = yb[gy * IMG]; }
    }

    block_sync_lgkm();   // sg + pad zeros visible; prefetch stays in flight
    f32x2 g2[11];
    #pragma unroll
    for (int k = 0; k < 11; ++k) { float gv = sg[k]; g2[k][0] = gv; g2[k][1] = gv; }

    const float C1 = 1.0e-4f;
    const float C2 = 9.0e-4f;
    float acc = 0.f;

    const int rr = tid & 7;            // h-conv row: varies within the wave
    const int c0 = (tid >> 3) * 8;     // h-conv output col base

    #pragma unroll 1
    for (int k = 0; k < NCHUNK; ++k) {
        if (k) {
            // Slide window down 8 rows; consume prefetched rows.
            #pragma unroll
            for (int j = 0; j < 10; ++j) pab[j] = pab[j + 8];
            #pragma unroll
            for (int j = 0; j < 8; ++j) {
                pab[10 + j][0] = pfa[j] + pfb[j];
                pab[10 + j][1] = pfa[j] - pfb[j];
            }
        }
        // Issue prefetch for chunk k+1's new rows; consumed next chunk, in
        // flight across both (non-draining) barriers.
        if (k < NCHUNK - 1) {
            int rbase = y0 + 8 * k + 13;
            #pragma unroll
            for (int j = 0; j < 8; ++j) {
                int gy = rbase + j;    // block-uniform
                pfa[j] = 0.f; pfb[j] = 0.f;
                if (gy < IMG) { pfa[j] = xb[gy * IMG]; pfb[j] = yb[gy * IMG]; }
            }
        }

        // Squares of the 18-row window.
        f32x2 sq[18];
        #pragma unroll
        for (int j = 0; j < 18; ++j) sq[j] = pk_mul(pab[j], pab[j]);

        // Vertical conv: 8 output rows -> LDS (stored col = image col + 5).
        #pragma unroll
        for (int i = 0; i < CHUNK; ++i) {
            f32x2 a = (f32x2)(0.f), q = (f32x2)(0.f);
            #pragma unroll
            for (int t = 0; t < 11; ++t) {
                a = pk_fma(g2[t], pab[i + t], a);
                q = pk_fma(g2[t], sq[i + t], q);
            }
            vab[i][tid + 5] = a;
            vqq[i][tid + 5] = q;
        }

        block_sync_lgkm();   // writes visible; vmcnt untouched

        // Horizontal conv + SSIM: 8 outputs per lane (row rr, cols c0..c0+7).
        // Out col c taps stored cols c..c+10; lane reads stored c0..c0+17
        // as 18 ds_read_b64 straight into pk_fma operands.
        {
            f32x2 mu[8], qq8[8];
            {
                const f32x2* p = &vab[rr][c0];
                f32x2 t[18];
                #pragma unroll
                for (int i = 0; i < 18; ++i) t[i] = p[i];
                #pragma unroll
                for (int i = 0; i < 8; ++i) {
                    f32x2 a = (f32x2)(0.f);
                    #pragma unroll
                    for (int t1 = 0; t1 < 11; ++t1) a = pk_fma(g2[t1], t[i + t1], a);
                    mu[i] = a;
                }
            }
            {
                const f32x2* p = &vqq[rr][c0];
                f32x2 t[18];
                #pragma unroll
                for (int i = 0; i < 18; ++i) t[i] = p[i];
                #pragma unroll
                for (int i = 0; i < 8; ++i) {
                    f32x2 a = (f32x2)(0.f);
                    #pragma unroll
                    for (int t1 = 0; t1 < 11; ++t1) a = pk_fma(g2[t1], t[i + t1], a);
                    qq8[i] = a;
                }
            }

            #pragma unroll
            for (int i = 0; i < 8; ++i) {
                // mu[i] = (ms, md); qq8[i] = (Ess, Edd)
                f32x2 m2 = pk_mul(mu[i], mu[i]);      // (ms^2, md^2)
                float P = m2[0] + m2[1];              // 2(mxx+myy)
                float Q = m2[0] - m2[1];              // 4 mxy
                float R = qq8[i][0] + qq8[i][1];      // 2(exx+eyy)
                float S = qq8[i][0] - qq8[i][1];      // 4 exy
                float num1 = fmaf(0.5f, Q, C1);
                float num2 = fmaf(0.5f, S - Q, C2);
                float den1 = fmaf(0.5f, P, C1);
                float den2 = fmaf(0.5f, R - P, C2);
                acc += (num1 * num2) * __builtin_amdgcn_rcpf(den1 * den2);
            }
        }

        // Reads done before next chunk's v-conv overwrites; vmcnt untouched.
        if (k < NCHUNK - 1) block_sync_lgkm();
    }

    // Block reduction (cold path: standard barrier fine).
    #pragma unroll
    for (int off = 32; off > 0; off >>= 1) acc += __shfl_down(acc, off, 64);
    int wid = tid >> 6, lane = tid & 63;
    if (lane == 0) redbuf[wid] = acc;
    __syncthreads();
    if (tid == 0) {
        float ssum = 0.f;
        #pragma unroll
        for (int w = 0; w < NTHREADS / 64; ++w) ssum += redbuf[w];
        partial[blockIdx.y * gridDim.x + blockIdx.x] = ssum;
    }
}

__global__ __launch_bounds__(512) void ssim_finalize(
    const float* __restrict__ partial, float* __restrict__ out)
{
    __shared__ double red[8];
    double acc = (double)partial[threadIdx.x];   // 512 partials (8 x 64 grid)
    #pragma unroll
    for (int off = 32; off > 0; off >>= 1) acc += __shfl_down(acc, off, 64);
    int wid = threadIdx.x >> 6, lane = threadIdx.x & 63;
    if (lane == 0) red[wid] = acc;
    __syncthreads();
    if (threadIdx.x == 0) {
        double ssum = 0.0;
        #pragma unroll
        for (int w = 0; w < 8; ++w) ssum += red[w];
        out[0] = (float)(ssum / (64.0 * 512.0 * 512.0));
    }
}

extern "C" void kernel_launch(void* const* d_in, const int* in_sizes, int n_in,
                              void* d_out, int out_size, void* d_ws, size_t ws_size,
                              hipStream_t stream) {
    (void)in_sizes; (void)n_in; (void)out_size; (void)ws_size;
    const float* x   = (const float*)d_in[0];
    const float* y   = (const float*)d_in[1];
    const float* win = (const float*)d_in[2];
    float* out = (float*)d_out;
    float* partial = (float*)d_ws;     // 512 floats

    dim3 grid(GRIDX, 64);              // 8 x 64 = 512 blocks, 2/CU, all resident
    ssim_band<<<grid, NTHREADS, 0, stream>>>(x, y, win, partial);
    ssim_finalize<<<1, 512, 0, stream>>>(partial, out);
}